// Round 13
// baseline (216.764 us; speedup 1.0000x reference)
//
#include <hip/hip_runtime.h>

#define NH 16
#define DEP 64
#define DM 1024
#define BB 4
#define SS 2048

typedef __attribute__((ext_vector_type(8))) __bf16 bf16x8;
typedef __attribute__((ext_vector_type(4))) __bf16 bf16x4;
typedef __attribute__((ext_vector_type(2))) __bf16 bf16x2;
typedef __attribute__((ext_vector_type(4))) float f32x4;
typedef __attribute__((ext_vector_type(4))) unsigned u32x4;
typedef __attribute__((ext_vector_type(2))) unsigned u32x2;
typedef unsigned short u16;

#define MFMA_BF16(A, B, C) __builtin_amdgcn_mfma_f32_16x16x32_bf16(A, B, C, 0, 0, 0)

// 0.125 * log2(e): QK^T scale folded into Q at projection time (exp2-domain softmax)
#define SCL 0.18033688011112042f
#define LOG2E 1.4426950408889634f

__device__ __forceinline__ u16 f2bf(float f) {
  unsigned u = __builtin_bit_cast(unsigned, f);
  u += 0x7fffu + ((u >> 16) & 1u);
  return (u16)(u >> 16);
}

__device__ __forceinline__ unsigned pk2(float a, float b) {
  bf16x2 t;
  t[0] = (__bf16)a; t[1] = (__bf16)b;
  return __builtin_bit_cast(unsigned, t);
}

__device__ __forceinline__ void gload_lds16(const u16* g, u16* l) {
  __builtin_amdgcn_global_load_lds((const __attribute__((address_space(1))) void*)g,
                                   (__attribute__((address_space(3))) void*)l, 16, 0, 0);
}

// ---- merged prep: cvt_x | pack_qkv | pack_wo | maskbias ----------------
// Flat grid 9248 blocks: [0,8192) cvt_x, [8192,8960) pack_qkv,
// [8960,9216) pack_wo, [9216,9248) maskbias. One launch instead of 4.
__global__ __launch_bounds__(256) void k_prep(const float* __restrict__ x, const float* __restrict__ mask,
                                              const float* __restrict__ Wq, const float* __restrict__ Wk,
                                              const float* __restrict__ Wv,
                                              const float* __restrict__ bq, const float* __restrict__ bk,
                                              const float* __restrict__ bv, const float* __restrict__ Wo,
                                              u16* __restrict__ xb, u16* __restrict__ wt,
                                              u16* __restrict__ wot, float* __restrict__ biasN,
                                              float* __restrict__ mb) {
  __shared__ float lt[64][65];
  const int bidg = blockIdx.x;
  const int t = threadIdx.x;
  if (bidg < 8192) {
    int i = (bidg * 256 + t) * 4;
    float4 v = *(const float4*)(x + i);
    ushort4 o;
    o.x = f2bf(v.x); o.y = f2bf(v.y); o.z = f2bf(v.z); o.w = f2bf(v.w);
    *(ushort4*)(xb + i) = o;
  } else if (bidg < 8960) {
    int z = bidg - 8192;               // 0..767
    int kx = z & 15, zy = z >> 4;      // zy 0..47
    int which = zy >> 4, h = zy & 15;
    int k0 = kx * 64;
    const float* W = which == 0 ? Wq : (which == 1 ? Wk : Wv);
    const float* bsrc = which == 0 ? bq : (which == 1 ? bk : bv);
    const float* src = W + (size_t)h * DM * DEP;   // [1024][64]
#pragma unroll
    for (int p = 0; p < 16; ++p) {
      int li = p * 256 + t;
      int r = li >> 6, c = li & 63;
      lt[r][c] = src[(size_t)(k0 + r) * 64 + c];
    }
    __syncthreads();
    int woff = which * DM + h * 64;
#pragma unroll
    for (int p = 0; p < 16; ++p) {
      int li = p * 256 + t;
      int r = li >> 6, c = li & 63;   // r = d, c = k_local
      wt[(size_t)(woff + r) * DM + k0 + c] = f2bf(lt[c][r]);
    }
    if (kx == 0 && t < 64) biasN[woff + t] = bsrc[h * 64 + t];
  } else if (bidg < 9216) {
    int z = bidg - 8960;               // 0..255
    int k0 = (z & 15) * 64, n0 = (z >> 4) * 64;
#pragma unroll
    for (int p = 0; p < 16; ++p) {
      int li = p * 256 + t;
      int r = li >> 6, c = li & 63;
      lt[r][c] = Wo[(size_t)(k0 + r) * DM + n0 + c];
    }
    __syncthreads();
#pragma unroll
    for (int p = 0; p < 16; ++p) {
      int li = p * 256 + t;
      int r = li >> 6, c = li & 63;
      wot[(size_t)(n0 + r) * DM + k0 + c] = f2bf(lt[c][r]);
    }
  } else {
    int i = (bidg - 9216) * 256 + t;   // 8192
    mb[i] = (1.0f - mask[i]) * (-1000000000.0f * LOG2E);
  }
}

// ---- QKV GEMM: [8192x1024]x[1024x3072], scatter epilogue ---------------
__global__ __launch_bounds__(256) void k_gemm_qkv(const u16* __restrict__ xb, const u16* __restrict__ wt,
                                                  const float* __restrict__ biasN,
                                                  u16* __restrict__ qb, u16* __restrict__ kb,
                                                  u16* __restrict__ vtb) {
  __shared__ u16 lA[2][128 * 32];
  __shared__ u16 lB[2][128 * 32];
  const int tid = threadIdx.x;
  const int lane = tid & 63, w = tid >> 6;
  const int m0 = blockIdx.x * 128, n0 = blockIdx.y * 128;
  const int wm = (w >> 1) * 64, wn = (w & 1) * 64;
  const int fr = lane & 15, fg = lane >> 4;
  const int bidx = tid * 16;
  const int row0 = bidx >> 6, c0 = (bidx & 63) >> 1;
  f32x4 acc[4][4] = {};
  auto stage = [&](int k0, int buf) {
    gload_lds16(xb + (size_t)(m0 + row0) * DM + k0 + c0, &lA[buf][w * 512]);
    gload_lds16(xb + (size_t)(m0 + row0 + 64) * DM + k0 + c0, &lA[buf][2048 + w * 512]);
    gload_lds16(wt + (size_t)(n0 + row0) * DM + k0 + c0, &lB[buf][w * 512]);
    gload_lds16(wt + (size_t)(n0 + row0 + 64) * DM + k0 + c0, &lB[buf][2048 + w * 512]);
  };
  stage(0, 0);
  __syncthreads();
  for (int k0 = 0; k0 < DM; k0 += 32) {
    const int cur = (k0 >> 5) & 1;
    if (k0 + 32 < DM) stage(k0 + 32, cur ^ 1);
    bf16x8 af[4], bfr[4];
#pragma unroll
    for (int i = 0; i < 4; ++i) {
      af[i] = *(const bf16x8*)&lA[cur][(wm + i * 16 + fr) * 32 + fg * 8];
      bfr[i] = *(const bf16x8*)&lB[cur][(wn + i * 16 + fr) * 32 + fg * 8];
    }
#pragma unroll
    for (int i = 0; i < 4; ++i)
#pragma unroll
      for (int j = 0; j < 4; ++j)
        acc[i][j] = MFMA_BF16(af[i], bfr[j], acc[i][j]);
    __syncthreads();
  }
#pragma unroll
  for (int i = 0; i < 4; ++i)
#pragma unroll
    for (int j = 0; j < 4; ++j) {
      int n = n0 + wn + j * 16 + fr;
      float bn = biasN[n];
      int which = n >> 10, rem = n & 1023, h = rem >> 6, d = rem & 63;
#pragma unroll
      for (int r = 0; r < 4; ++r) {
        int m = m0 + wm + i * 16 + fg * 4 + r;
        int b = m >> 11, s = m & 2047;
        float val = acc[i][j][r] + bn;
        if (which == 0)      qb[(((size_t)(b * NH + h) * SS + s) << 6) + d] = f2bf(val * SCL);
        else if (which == 1) kb[(((size_t)(b * NH + h) * SS + s) << 6) + d] = f2bf(val);
        else                 vtb[(((size_t)(b * NH + h) * 64 + d) << 11) + s] = f2bf(val);
      }
    }
}

// ---- flash attention (R12 body + qf software pipeline) -----------------
// 4 waves x 64 q-rows, KVBLK=64, 2-phase LDS dbuf, XCD-affinity grid,
// no P bounce, no-max softmax. NEW: the 4 independent qf chains are
// software-pipelined — QK(qf+1)'s 8 MFMAs issue BEFORE SM+PV(qf)'s
// exp2/pack/PV chain, so the MFMA pipe has independent work to co-issue
// with the VALU chain (R12 showed pipes fully serialized: 29%+38%+28%
// summed to dur). Two named sc arrays, all-static indexing (rule #20).
// mask-bias loads hoisted to tile level (qf-invariant).
__global__ __launch_bounds__(256, 2) void k_attn(const u16* __restrict__ qb, const u16* __restrict__ kb,
                                                 const u16* __restrict__ vtb, const float* __restrict__ mbias,
                                                 u16* __restrict__ zb) {
  __shared__ u16 sK[2][64 * 64];   // [kvrow][d], swizzled 16B groups
  __shared__ u16 sV[2][64 * 64];   // [d][s_local], swizzled 16B groups
  const int bid = blockIdx.x;
  const int sw = (bid & 7) * 64 + (bid >> 3);    // bijective: 512 = 8*64
  const int bh = sw >> 3;                        // 8 q-blocks of bh share bid%8 -> same XCD
  const int qx = sw & 7;
  const int b = bh >> 4, h = bh & 15;
  const int tid = threadIdx.x, lane = tid & 63, w = tid >> 6;
  const int q0 = qx * 256 + w * 64;
  const u16* Q  = qb  + (size_t)bh * SS * 64;
  const u16* K  = kb  + (size_t)bh * SS * 64;
  const u16* VT = vtb + (size_t)bh * 64 * SS;
  const float* mbb = mbias + b * SS;
  const int fr = lane & 15, fg = lane >> 4;
  const int fr7 = fr & 7;
  const int rsub = lane >> 3;           // 0..7
  const int cg = (lane & 7) ^ rsub;     // pre-swizzled source col group (16B units)
  const int kc0 = (fg ^ fr7) * 16;
  const int kc1 = ((4 + fg) ^ fr7) * 16;
  const int fg1 = fg >> 1, fgb = (fg & 1) * 8;
  const int cX0 = (((fg1)     ^ fr7)) * 16 + fgb;       // k = 4fg..+3
  const int cX1 = (((2 + (fg1 ^ 1)) ^ fr7)) * 16 + fgb; // k = 16+4(fg^2)..+3
  const int cY0 = (((4 + fg1) ^ fr7)) * 16 + fgb;       // k = 32+4fg..+3
  const int cY1 = (((6 + (fg1 ^ 1)) ^ fr7)) * 16 + fgb; // k = 48+4(fg^2)..+3
  bf16x8 qlo[4], qhi[4];
#pragma unroll
  for (int qf = 0; qf < 4; ++qf) {
    qlo[qf] = *(const bf16x8*)&Q[(q0 + 16 * qf + fr) * 64 + fg * 8];
    qhi[qf] = *(const bf16x8*)&Q[(q0 + 16 * qf + fr) * 64 + 32 + fg * 8];
  }
  float lrun[4] = {0.f, 0.f, 0.f, 0.f};
  f32x4 o[4][4] = {};

  // prologue: stage tile 0 into buf 0
#pragma unroll
  for (int j = 0; j < 2; ++j) {
    int i = w * 2 + j;
    gload_lds16(K + (size_t)(8 * i + rsub) * 64 + cg * 8, &sK[0][i * 512]);
    gload_lds16(VT + (size_t)(8 * i + rsub) * SS + cg * 8, &sV[0][i * 512]);
  }
  __syncthreads();

  for (int t = 0; t < 32; ++t) {
    const int cur = t & 1;
    if (t < 31) {
      const int kvn = (t + 1) * 64;
#pragma unroll
      for (int j = 0; j < 2; ++j) {
        int i = w * 2 + j;
        gload_lds16(K + (size_t)(kvn + 8 * i + rsub) * 64 + cg * 8, &sK[cur ^ 1][i * 512]);
        gload_lds16(VT + (size_t)(8 * i + rsub) * SS + kvn + cg * 8, &sV[cur ^ 1][i * 512]);
      }
    }
    const int kv = t * 64;
    const char* Kb = (const char*)&sK[cur][0];
    const char* Vb = (const char*)&sV[cur][0];
    // tile-level loads, shared by all 4 q-frags
    f32x4 mbv[4];
#pragma unroll
    for (int kt = 0; kt < 4; ++kt) mbv[kt] = *(const f32x4*)(mbb + kv + kt * 16 + fg * 4);
    bf16x8 klo[4], khi[4];
#pragma unroll
    for (int kt = 0; kt < 4; ++kt) {
      klo[kt] = *(const bf16x8*)(Kb + (kt * 16 + fr) * 128 + kc0);
      khi[kt] = *(const bf16x8*)(Kb + (kt * 16 + fr) * 128 + kc1);
    }
    bf16x8 vX[4], vY[4];
#pragma unroll
    for (int dc = 0; dc < 4; ++dc) {
      const char* rb = Vb + (dc * 16 + fr) * 128;
      u32x2 a0 = *(const u32x2*)(rb + cX0);
      u32x2 a1 = *(const u32x2*)(rb + cX1);
      u32x2 b0 = *(const u32x2*)(rb + cY0);
      u32x2 b1 = *(const u32x2*)(rb + cY1);
      u32x4 ua = {a0[0], a0[1], a1[0], a1[1]};
      u32x4 ub = {b0[0], b0[1], b1[0], b1[1]};
      vX[dc] = __builtin_bit_cast(bf16x8, ua);
      vY[dc] = __builtin_bit_cast(bf16x8, ub);
    }

    auto QKf = [&](int qf, f32x4 (&sc)[4]) {
      __builtin_amdgcn_s_setprio(1);
#pragma unroll
      for (int kt = 0; kt < 4; ++kt)
        sc[kt] = MFMA_BF16(khi[kt], qhi[qf], MFMA_BF16(klo[kt], qlo[qf], mbv[kt]));
      __builtin_amdgcn_s_setprio(0);
    };
    auto SMPV = [&](int qf, f32x4 (&sc)[4]) {
      float e00 = __builtin_amdgcn_exp2f(sc[0][0]), e01 = __builtin_amdgcn_exp2f(sc[0][1]);
      float e02 = __builtin_amdgcn_exp2f(sc[0][2]), e03 = __builtin_amdgcn_exp2f(sc[0][3]);
      float e10 = __builtin_amdgcn_exp2f(sc[1][0]), e11 = __builtin_amdgcn_exp2f(sc[1][1]);
      float e12 = __builtin_amdgcn_exp2f(sc[1][2]), e13 = __builtin_amdgcn_exp2f(sc[1][3]);
      float e20 = __builtin_amdgcn_exp2f(sc[2][0]), e21 = __builtin_amdgcn_exp2f(sc[2][1]);
      float e22 = __builtin_amdgcn_exp2f(sc[2][2]), e23 = __builtin_amdgcn_exp2f(sc[2][3]);
      float e30 = __builtin_amdgcn_exp2f(sc[3][0]), e31 = __builtin_amdgcn_exp2f(sc[3][1]);
      float e32 = __builtin_amdgcn_exp2f(sc[3][2]), e33 = __builtin_amdgcn_exp2f(sc[3][3]);
      lrun[qf] += ((e00 + e01) + (e02 + e03)) + ((e10 + e11) + (e12 + e13))
                + ((e20 + e21) + (e22 + e23)) + ((e30 + e31) + (e32 + e33));
      unsigned w00 = pk2(e00, e01), w01 = pk2(e02, e03);
      unsigned w10 = pk2(e10, e11), w11 = pk2(e12, e13);
      unsigned w20 = pk2(e20, e21), w21 = pk2(e22, e23);
      unsigned w30 = pk2(e30, e31), w31 = pk2(e32, e33);
      unsigned x2 = (unsigned)__shfl_xor((int)w10, 32);
      unsigned x3 = (unsigned)__shfl_xor((int)w11, 32);
      unsigned y2 = (unsigned)__shfl_xor((int)w30, 32);
      unsigned y3 = (unsigned)__shfl_xor((int)w31, 32);
      u32x4 ux = {w00, w01, x2, x3};
      u32x4 uy = {w20, w21, y2, y3};
      bf16x8 paX = __builtin_bit_cast(bf16x8, ux);
      bf16x8 paY = __builtin_bit_cast(bf16x8, uy);
      __builtin_amdgcn_s_setprio(1);
#pragma unroll
      for (int dc = 0; dc < 4; ++dc) {
        o[qf][dc] = MFMA_BF16(paX, vX[dc], o[qf][dc]);
        o[qf][dc] = MFMA_BF16(paY, vY[dc], o[qf][dc]);
      }
      __builtin_amdgcn_s_setprio(0);
    };

    // software pipeline over the 4 independent qf chains:
    // QK(qf+1) MFMAs are in flight while SM+PV(qf) runs on the VALU.
    f32x4 scA[4], scB[4];
    QKf(0, scA);
    QKf(1, scB); SMPV(0, scA);
    QKf(2, scA); SMPV(1, scB);
    QKf(3, scB); SMPV(2, scA);
    SMPV(3, scB);

    __syncthreads();   // all waves done reading cur; next stage drained
  }
#pragma unroll
  for (int qf = 0; qf < 4; ++qf) {
    float l = lrun[qf];
    l += __shfl_xor(l, 16);
    l += __shfl_xor(l, 32);
#pragma unroll
    for (int r = 0; r < 4; ++r) {
      float linv = 1.0f / __shfl(l, 4 * fg + r);
      int s = q0 + 16 * qf + 4 * fg + r;
#pragma unroll
      for (int dc = 0; dc < 4; ++dc)
        zb[(size_t)(b * SS + s) * DM + h * 64 + dc * 16 + fr] = f2bf(o[qf][dc][r] * linv);
    }
  }
}

// ---- output GEMM: [8192x1024]x[1024x1024] + bo -> fp32 out -------------
__global__ __launch_bounds__(256) void k_gemm_out(const u16* __restrict__ zb, const u16* __restrict__ wot,
                                                  const float* __restrict__ bo, float* __restrict__ out) {
  __shared__ u16 lA[2][128 * 32];
  __shared__ u16 lB[2][128 * 32];
  const int tid = threadIdx.x;
  const int lane = tid & 63, w = tid >> 6;
  const int m0 = blockIdx.x * 128, n0 = blockIdx.y * 128;
  const int wm = (w >> 1) * 64, wn = (w & 1) * 64;
  const int fr = lane & 15, fg = lane >> 4;
  const int bidx = tid * 16;
  const int row0 = bidx >> 6, c0 = (bidx & 63) >> 1;
  f32x4 acc[4][4] = {};
  auto stage = [&](int k0, int buf) {
    gload_lds16(zb + (size_t)(m0 + row0) * DM + k0 + c0, &lA[buf][w * 512]);
    gload_lds16(zb + (size_t)(m0 + row0 + 64) * DM + k0 + c0, &lA[buf][2048 + w * 512]);
    gload_lds16(wot + (size_t)(n0 + row0) * DM + k0 + c0, &lB[buf][w * 512]);
    gload_lds16(wot + (size_t)(n0 + row0 + 64) * DM + k0 + c0, &lB[buf][2048 + w * 512]);
  };
  stage(0, 0);
  __syncthreads();
  for (int k0 = 0; k0 < DM; k0 += 32) {
    const int cur = (k0 >> 5) & 1;
    if (k0 + 32 < DM) stage(k0 + 32, cur ^ 1);
    bf16x8 af[4], bfr[4];
#pragma unroll
    for (int i = 0; i < 4; ++i) {
      af[i] = *(const bf16x8*)&lA[cur][(wm + i * 16 + fr) * 32 + fg * 8];
      bfr[i] = *(const bf16x8*)&lB[cur][(wn + i * 16 + fr) * 32 + fg * 8];
    }
#pragma unroll
    for (int i = 0; i < 4; ++i)
#pragma unroll
      for (int j = 0; j < 4; ++j)
        acc[i][j] = MFMA_BF16(af[i], bfr[j], acc[i][j]);
    __syncthreads();
  }
#pragma unroll
  for (int i = 0; i < 4; ++i)
#pragma unroll
    for (int j = 0; j < 4; ++j) {
      int n = n0 + wn + j * 16 + fr;
      float bn = bo[n];
#pragma unroll
      for (int r = 0; r < 4; ++r) {
        int m = m0 + wm + i * 16 + fg * 4 + r;
        out[(size_t)m * DM + n] = acc[i][j][r] + bn;
      }
    }
}

extern "C" void kernel_launch(void* const* d_in, const int* in_sizes, int n_in,
                              void* d_out, int out_size, void* d_ws, size_t ws_size,
                              hipStream_t stream) {
  const float* x    = (const float*)d_in[0];
  const float* mask = (const float*)d_in[1];
  const float* Wq   = (const float*)d_in[2];
  const float* bq   = (const float*)d_in[3];
  const float* Wk   = (const float*)d_in[4];
  const float* bk   = (const float*)d_in[5];
  const float* Wv   = (const float*)d_in[6];
  const float* bv   = (const float*)d_in[7];
  const float* Wo   = (const float*)d_in[8];
  const float* bo   = (const float*)d_in[9];
  char* ws = (char*)d_ws;
  u16*   xb    = (u16*)(ws + 0);          // 16.78 MB, reused as zb after QKV GEMM
  u16*   zb    = xb;
  u16*   wt    = (u16*)(ws + 16777216);   // 6.29 MB
  u16*   wot   = (u16*)(ws + 23068672);   // 2.10 MB
  float* biasN = (float*)(ws + 25165824); // 12 KB
  float* mb    = (float*)(ws + 25178112); // 32 KB
  u16*   qb    = (u16*)(ws + 25210880);   // 16.78 MB
  u16*   kb    = (u16*)(ws + 41988096);   // 16.78 MB
  u16*   vtb   = (u16*)(ws + 58765312);   // 16.78 MB
  float* out   = (float*)d_out;

  k_prep<<<dim3(9248), dim3(256), 0, stream>>>(x, mask, Wq, Wk, Wv, bq, bk, bv, Wo,
                                               xb, wt, wot, biasN, mb);
  k_gemm_qkv<<<dim3(64, 24), dim3(256), 0, stream>>>(xb, wt, biasN, qb, kb, vtb);
  k_attn<<<dim3(512), dim3(256), 0, stream>>>(qb, kb, vtb, mb, zb);
  k_gemm_out<<<dim3(64, 8), dim3(256), 0, stream>>>(zb, wot, bo, out);
}

// Round 14
// 207.652 us; speedup vs baseline: 1.0439x; 1.0439x over previous
//
#include <hip/hip_runtime.h>

#define NH 16
#define DEP 64
#define DM 1024
#define BB 4
#define SS 2048

typedef __attribute__((ext_vector_type(8))) __bf16 bf16x8;
typedef __attribute__((ext_vector_type(4))) __bf16 bf16x4;
typedef __attribute__((ext_vector_type(2))) __bf16 bf16x2;
typedef __attribute__((ext_vector_type(4))) float f32x4;
typedef __attribute__((ext_vector_type(4))) unsigned u32x4;
typedef __attribute__((ext_vector_type(2))) unsigned u32x2;
typedef unsigned short u16;

#define MFMA_BF16(A, B, C) __builtin_amdgcn_mfma_f32_16x16x32_bf16(A, B, C, 0, 0, 0)

// 0.125 * log2(e): QK^T scale folded into Q at projection time (exp2-domain softmax)
#define SCL 0.18033688011112042f
#define LOG2E 1.4426950408889634f

__device__ __forceinline__ u16 f2bf(float f) {
  unsigned u = __builtin_bit_cast(unsigned, f);
  u += 0x7fffu + ((u >> 16) & 1u);
  return (u16)(u >> 16);
}

__device__ __forceinline__ unsigned pk2(float a, float b) {
  bf16x2 t;
  t[0] = (__bf16)a; t[1] = (__bf16)b;
  return __builtin_bit_cast(unsigned, t);
}

__device__ __forceinline__ void gload_lds16(const u16* g, u16* l) {
  __builtin_amdgcn_global_load_lds((const __attribute__((address_space(1))) void*)g,
                                   (__attribute__((address_space(3))) void*)l, 16, 0, 0);
}

// ---- merged prep: cvt_x | pack_qkv | pack_wo | maskbias ----------------
// Flat grid 9248 blocks: [0,8192) cvt_x, [8192,8960) pack_qkv,
// [8960,9216) pack_wo, [9216,9248) maskbias. One launch instead of 4.
__global__ __launch_bounds__(256) void k_prep(const float* __restrict__ x, const float* __restrict__ mask,
                                              const float* __restrict__ Wq, const float* __restrict__ Wk,
                                              const float* __restrict__ Wv,
                                              const float* __restrict__ bq, const float* __restrict__ bk,
                                              const float* __restrict__ bv, const float* __restrict__ Wo,
                                              u16* __restrict__ xb, u16* __restrict__ wt,
                                              u16* __restrict__ wot, float* __restrict__ biasN,
                                              float* __restrict__ mb) {
  __shared__ float lt[64][65];
  const int bidg = blockIdx.x;
  const int t = threadIdx.x;
  if (bidg < 8192) {
    int i = (bidg * 256 + t) * 4;
    float4 v = *(const float4*)(x + i);
    ushort4 o;
    o.x = f2bf(v.x); o.y = f2bf(v.y); o.z = f2bf(v.z); o.w = f2bf(v.w);
    *(ushort4*)(xb + i) = o;
  } else if (bidg < 8960) {
    int z = bidg - 8192;               // 0..767
    int kx = z & 15, zy = z >> 4;      // zy 0..47
    int which = zy >> 4, h = zy & 15;
    int k0 = kx * 64;
    const float* W = which == 0 ? Wq : (which == 1 ? Wk : Wv);
    const float* bsrc = which == 0 ? bq : (which == 1 ? bk : bv);
    const float* src = W + (size_t)h * DM * DEP;   // [1024][64]
#pragma unroll
    for (int p = 0; p < 16; ++p) {
      int li = p * 256 + t;
      int r = li >> 6, c = li & 63;
      lt[r][c] = src[(size_t)(k0 + r) * 64 + c];
    }
    __syncthreads();
    int woff = which * DM + h * 64;
#pragma unroll
    for (int p = 0; p < 16; ++p) {
      int li = p * 256 + t;
      int r = li >> 6, c = li & 63;   // r = d, c = k_local
      wt[(size_t)(woff + r) * DM + k0 + c] = f2bf(lt[c][r]);
    }
    if (kx == 0 && t < 64) biasN[woff + t] = bsrc[h * 64 + t];
  } else if (bidg < 9216) {
    int z = bidg - 8960;               // 0..255
    int k0 = (z & 15) * 64, n0 = (z >> 4) * 64;
#pragma unroll
    for (int p = 0; p < 16; ++p) {
      int li = p * 256 + t;
      int r = li >> 6, c = li & 63;
      lt[r][c] = Wo[(size_t)(k0 + r) * DM + n0 + c];
    }
    __syncthreads();
#pragma unroll
    for (int p = 0; p < 16; ++p) {
      int li = p * 256 + t;
      int r = li >> 6, c = li & 63;
      wot[(size_t)(n0 + r) * DM + k0 + c] = f2bf(lt[c][r]);
    }
  } else {
    int i = (bidg - 9216) * 256 + t;   // 8192
    mb[i] = (1.0f - mask[i]) * (-1000000000.0f * LOG2E);
  }
}

// ---- QKV GEMM: [8192x1024]x[1024x3072], scatter epilogue ---------------
__global__ __launch_bounds__(256) void k_gemm_qkv(const u16* __restrict__ xb, const u16* __restrict__ wt,
                                                  const float* __restrict__ biasN,
                                                  u16* __restrict__ qb, u16* __restrict__ kb,
                                                  u16* __restrict__ vtb) {
  __shared__ u16 lA[2][128 * 32];
  __shared__ u16 lB[2][128 * 32];
  const int tid = threadIdx.x;
  const int lane = tid & 63, w = tid >> 6;
  const int m0 = blockIdx.x * 128, n0 = blockIdx.y * 128;
  const int wm = (w >> 1) * 64, wn = (w & 1) * 64;
  const int fr = lane & 15, fg = lane >> 4;
  const int bidx = tid * 16;
  const int row0 = bidx >> 6, c0 = (bidx & 63) >> 1;
  f32x4 acc[4][4] = {};
  auto stage = [&](int k0, int buf) {
    gload_lds16(xb + (size_t)(m0 + row0) * DM + k0 + c0, &lA[buf][w * 512]);
    gload_lds16(xb + (size_t)(m0 + row0 + 64) * DM + k0 + c0, &lA[buf][2048 + w * 512]);
    gload_lds16(wt + (size_t)(n0 + row0) * DM + k0 + c0, &lB[buf][w * 512]);
    gload_lds16(wt + (size_t)(n0 + row0 + 64) * DM + k0 + c0, &lB[buf][2048 + w * 512]);
  };
  stage(0, 0);
  __syncthreads();
  for (int k0 = 0; k0 < DM; k0 += 32) {
    const int cur = (k0 >> 5) & 1;
    if (k0 + 32 < DM) stage(k0 + 32, cur ^ 1);
    bf16x8 af[4], bfr[4];
#pragma unroll
    for (int i = 0; i < 4; ++i) {
      af[i] = *(const bf16x8*)&lA[cur][(wm + i * 16 + fr) * 32 + fg * 8];
      bfr[i] = *(const bf16x8*)&lB[cur][(wn + i * 16 + fr) * 32 + fg * 8];
    }
#pragma unroll
    for (int i = 0; i < 4; ++i)
#pragma unroll
      for (int j = 0; j < 4; ++j)
        acc[i][j] = MFMA_BF16(af[i], bfr[j], acc[i][j]);
    __syncthreads();
  }
#pragma unroll
  for (int i = 0; i < 4; ++i)
#pragma unroll
    for (int j = 0; j < 4; ++j) {
      int n = n0 + wn + j * 16 + fr;
      float bn = biasN[n];
      int which = n >> 10, rem = n & 1023, h = rem >> 6, d = rem & 63;
#pragma unroll
      for (int r = 0; r < 4; ++r) {
        int m = m0 + wm + i * 16 + fg * 4 + r;
        int b = m >> 11, s = m & 2047;
        float val = acc[i][j][r] + bn;
        if (which == 0)      qb[(((size_t)(b * NH + h) * SS + s) << 6) + d] = f2bf(val * SCL);
        else if (which == 1) kb[(((size_t)(b * NH + h) * SS + s) << 6) + d] = f2bf(val);
        else                 vtb[(((size_t)(b * NH + h) * 64 + d) << 11) + s] = f2bf(val);
      }
    }
}

// ---- flash attention (R12-exact body: best measured, 98.6 us) ----------
// 4 waves x 64 q-rows (4 q-frags), KVBLK=64, 2-phase LDS K/V dbuf,
// XCD-affinity grid (FETCH 139->25MB proven), no P LDS bounce (xor32
// k-slot permutation), no-max softmax. R13's qf-pipeline variant spilled
// (compiler pins 128 VGPR at (256,2) and spills rather than exceed) and
// regressed 98.6->108; reverted.
__global__ __launch_bounds__(256, 2) void k_attn(const u16* __restrict__ qb, const u16* __restrict__ kb,
                                                 const u16* __restrict__ vtb, const float* __restrict__ mbias,
                                                 u16* __restrict__ zb) {
  __shared__ u16 sK[2][64 * 64];   // [kvrow][d], swizzled 16B groups
  __shared__ u16 sV[2][64 * 64];   // [d][s_local], swizzled 16B groups
  const int bid = blockIdx.x;
  const int sw = (bid & 7) * 64 + (bid >> 3);    // bijective: 512 = 8*64
  const int bh = sw >> 3;                        // 8 q-blocks of bh share bid%8 -> same XCD
  const int qx = sw & 7;
  const int b = bh >> 4, h = bh & 15;
  const int tid = threadIdx.x, lane = tid & 63, w = tid >> 6;
  const int q0 = qx * 256 + w * 64;
  const u16* Q  = qb  + (size_t)bh * SS * 64;
  const u16* K  = kb  + (size_t)bh * SS * 64;
  const u16* VT = vtb + (size_t)bh * 64 * SS;
  const float* mbb = mbias + b * SS;
  const int fr = lane & 15, fg = lane >> 4;
  const int fr7 = fr & 7;
  const int rsub = lane >> 3;           // 0..7
  const int cg = (lane & 7) ^ rsub;     // pre-swizzled source col group (16B units)
  const int kc0 = (fg ^ fr7) * 16;
  const int kc1 = ((4 + fg) ^ fr7) * 16;
  const int fg1 = fg >> 1, fgb = (fg & 1) * 8;
  const int cX0 = (((fg1)     ^ fr7)) * 16 + fgb;   // k = 4fg..+3
  const int cX1 = (((2 + (fg1 ^ 1)) ^ fr7)) * 16 + fgb; // k = 16+4(fg^2)..+3
  const int cY0 = (((4 + fg1) ^ fr7)) * 16 + fgb;   // k = 32+4fg..+3
  const int cY1 = (((6 + (fg1 ^ 1)) ^ fr7)) * 16 + fgb; // k = 48+4(fg^2)..+3
  bf16x8 qlo[4], qhi[4];
#pragma unroll
  for (int qf = 0; qf < 4; ++qf) {
    qlo[qf] = *(const bf16x8*)&Q[(q0 + 16 * qf + fr) * 64 + fg * 8];
    qhi[qf] = *(const bf16x8*)&Q[(q0 + 16 * qf + fr) * 64 + 32 + fg * 8];
  }
  float lrun[4] = {0.f, 0.f, 0.f, 0.f};
  f32x4 o[4][4] = {};

  // prologue: stage tile 0 into buf 0
#pragma unroll
  for (int j = 0; j < 2; ++j) {
    int i = w * 2 + j;
    gload_lds16(K + (size_t)(8 * i + rsub) * 64 + cg * 8, &sK[0][i * 512]);
    gload_lds16(VT + (size_t)(8 * i + rsub) * SS + cg * 8, &sV[0][i * 512]);
  }
  __syncthreads();

  for (int t = 0; t < 32; ++t) {
    const int cur = t & 1;
    if (t < 31) {
      const int kvn = (t + 1) * 64;
#pragma unroll
      for (int j = 0; j < 2; ++j) {
        int i = w * 2 + j;
        gload_lds16(K + (size_t)(kvn + 8 * i + rsub) * 64 + cg * 8, &sK[cur ^ 1][i * 512]);
        gload_lds16(VT + (size_t)(8 * i + rsub) * SS + kvn + cg * 8, &sV[cur ^ 1][i * 512]);
      }
    }
    const int kv = t * 64;
    const char* Kb = (const char*)&sK[cur][0];
    const char* Vb = (const char*)&sV[cur][0];
    // K fragments (shared across the 4 q-frags)
    bf16x8 klo[4], khi[4];
#pragma unroll
    for (int kt = 0; kt < 4; ++kt) {
      klo[kt] = *(const bf16x8*)(Kb + (kt * 16 + fr) * 128 + kc0);
      khi[kt] = *(const bf16x8*)(Kb + (kt * 16 + fr) * 128 + kc1);
    }
    // V b64 words (shared across the 4 q-frags)
    u32x2 vx0[4], vx1[4], vy0[4], vy1[4];
#pragma unroll
    for (int dc = 0; dc < 4; ++dc) {
      const char* rb = Vb + (dc * 16 + fr) * 128;
      vx0[dc] = *(const u32x2*)(rb + cX0);
      vx1[dc] = *(const u32x2*)(rb + cX1);
      vy0[dc] = *(const u32x2*)(rb + cY0);
      vy1[dc] = *(const u32x2*)(rb + cY1);
    }
#pragma unroll
    for (int qf = 0; qf < 4; ++qf) {
      f32x4 sc[4];
      __builtin_amdgcn_s_setprio(1);
#pragma unroll
      for (int kt = 0; kt < 4; ++kt) {
        f32x4 mb4 = *(const f32x4*)(mbb + kv + kt * 16 + fg * 4);
        sc[kt] = MFMA_BF16(khi[kt], qhi[qf], MFMA_BF16(klo[kt], qlo[qf], mb4));
      }
      __builtin_amdgcn_s_setprio(0);
      // no-max softmax: P = exp2(s); per-lane partial denominator
      float e00 = __builtin_amdgcn_exp2f(sc[0][0]), e01 = __builtin_amdgcn_exp2f(sc[0][1]);
      float e02 = __builtin_amdgcn_exp2f(sc[0][2]), e03 = __builtin_amdgcn_exp2f(sc[0][3]);
      float e10 = __builtin_amdgcn_exp2f(sc[1][0]), e11 = __builtin_amdgcn_exp2f(sc[1][1]);
      float e12 = __builtin_amdgcn_exp2f(sc[1][2]), e13 = __builtin_amdgcn_exp2f(sc[1][3]);
      float e20 = __builtin_amdgcn_exp2f(sc[2][0]), e21 = __builtin_amdgcn_exp2f(sc[2][1]);
      float e22 = __builtin_amdgcn_exp2f(sc[2][2]), e23 = __builtin_amdgcn_exp2f(sc[2][3]);
      float e30 = __builtin_amdgcn_exp2f(sc[3][0]), e31 = __builtin_amdgcn_exp2f(sc[3][1]);
      float e32 = __builtin_amdgcn_exp2f(sc[3][2]), e33 = __builtin_amdgcn_exp2f(sc[3][3]);
      lrun[qf] += ((e00 + e01) + (e02 + e03)) + ((e10 + e11) + (e12 + e13))
                + ((e20 + e21) + (e22 + e23)) + ((e30 + e31) + (e32 + e33));
      unsigned w00 = pk2(e00, e01), w01 = pk2(e02, e03);
      unsigned w10 = pk2(e10, e11), w11 = pk2(e12, e13);
      unsigned w20 = pk2(e20, e21), w21 = pk2(e22, e23);
      unsigned w30 = pk2(e30, e31), w31 = pk2(e32, e33);
      // xor32 exchange: partner's kt=1 words (fragment X) and kt=3 (Y)
      unsigned x2 = (unsigned)__shfl_xor((int)w10, 32);
      unsigned x3 = (unsigned)__shfl_xor((int)w11, 32);
      unsigned y2 = (unsigned)__shfl_xor((int)w30, 32);
      unsigned y3 = (unsigned)__shfl_xor((int)w31, 32);
      u32x4 ux = {w00, w01, x2, x3};
      u32x4 uy = {w20, w21, y2, y3};
      bf16x8 paX = __builtin_bit_cast(bf16x8, ux);
      bf16x8 paY = __builtin_bit_cast(bf16x8, uy);
      __builtin_amdgcn_s_setprio(1);
#pragma unroll
      for (int dc = 0; dc < 4; ++dc) {
        u32x4 vxw = {vx0[dc][0], vx0[dc][1], vx1[dc][0], vx1[dc][1]};
        u32x4 vyw = {vy0[dc][0], vy0[dc][1], vy1[dc][0], vy1[dc][1]};
        bf16x8 vX = __builtin_bit_cast(bf16x8, vxw);
        bf16x8 vY = __builtin_bit_cast(bf16x8, vyw);
        o[qf][dc] = MFMA_BF16(paX, vX, o[qf][dc]);
        o[qf][dc] = MFMA_BF16(paY, vY, o[qf][dc]);
      }
      __builtin_amdgcn_s_setprio(0);
    }
    __syncthreads();   // all waves done reading cur; next stage drained
  }
#pragma unroll
  for (int qf = 0; qf < 4; ++qf) {
    float l = lrun[qf];
    l += __shfl_xor(l, 16);
    l += __shfl_xor(l, 32);
#pragma unroll
    for (int r = 0; r < 4; ++r) {
      float linv = 1.0f / __shfl(l, 4 * fg + r);
      int s = q0 + 16 * qf + 4 * fg + r;
#pragma unroll
      for (int dc = 0; dc < 4; ++dc)
        zb[(size_t)(b * SS + s) * DM + h * 64 + dc * 16 + fr] = f2bf(o[qf][dc][r] * linv);
    }
  }
}

// ---- output GEMM: [8192x1024]x[1024x1024] + bo -> fp32 out -------------
__global__ __launch_bounds__(256) void k_gemm_out(const u16* __restrict__ zb, const u16* __restrict__ wot,
                                                  const float* __restrict__ bo, float* __restrict__ out) {
  __shared__ u16 lA[2][128 * 32];
  __shared__ u16 lB[2][128 * 32];
  const int tid = threadIdx.x;
  const int lane = tid & 63, w = tid >> 6;
  const int m0 = blockIdx.x * 128, n0 = blockIdx.y * 128;
  const int wm = (w >> 1) * 64, wn = (w & 1) * 64;
  const int fr = lane & 15, fg = lane >> 4;
  const int bidx = tid * 16;
  const int row0 = bidx >> 6, c0 = (bidx & 63) >> 1;
  f32x4 acc[4][4] = {};
  auto stage = [&](int k0, int buf) {
    gload_lds16(zb + (size_t)(m0 + row0) * DM + k0 + c0, &lA[buf][w * 512]);
    gload_lds16(zb + (size_t)(m0 + row0 + 64) * DM + k0 + c0, &lA[buf][2048 + w * 512]);
    gload_lds16(wot + (size_t)(n0 + row0) * DM + k0 + c0, &lB[buf][w * 512]);
    gload_lds16(wot + (size_t)(n0 + row0 + 64) * DM + k0 + c0, &lB[buf][2048 + w * 512]);
  };
  stage(0, 0);
  __syncthreads();
  for (int k0 = 0; k0 < DM; k0 += 32) {
    const int cur = (k0 >> 5) & 1;
    if (k0 + 32 < DM) stage(k0 + 32, cur ^ 1);
    bf16x8 af[4], bfr[4];
#pragma unroll
    for (int i = 0; i < 4; ++i) {
      af[i] = *(const bf16x8*)&lA[cur][(wm + i * 16 + fr) * 32 + fg * 8];
      bfr[i] = *(const bf16x8*)&lB[cur][(wn + i * 16 + fr) * 32 + fg * 8];
    }
#pragma unroll
    for (int i = 0; i < 4; ++i)
#pragma unroll
      for (int j = 0; j < 4; ++j)
        acc[i][j] = MFMA_BF16(af[i], bfr[j], acc[i][j]);
    __syncthreads();
  }
#pragma unroll
  for (int i = 0; i < 4; ++i)
#pragma unroll
    for (int j = 0; j < 4; ++j) {
      int n = n0 + wn + j * 16 + fr;
      float bn = bo[n];
#pragma unroll
      for (int r = 0; r < 4; ++r) {
        int m = m0 + wm + i * 16 + fg * 4 + r;
        out[(size_t)m * DM + n] = acc[i][j][r] + bn;
      }
    }
}

extern "C" void kernel_launch(void* const* d_in, const int* in_sizes, int n_in,
                              void* d_out, int out_size, void* d_ws, size_t ws_size,
                              hipStream_t stream) {
  const float* x    = (const float*)d_in[0];
  const float* mask = (const float*)d_in[1];
  const float* Wq   = (const float*)d_in[2];
  const float* bq   = (const float*)d_in[3];
  const float* Wk   = (const float*)d_in[4];
  const float* bk   = (const float*)d_in[5];
  const float* Wv   = (const float*)d_in[6];
  const float* bv   = (const float*)d_in[7];
  const float* Wo   = (const float*)d_in[8];
  const float* bo   = (const float*)d_in[9];
  char* ws = (char*)d_ws;
  u16*   xb    = (u16*)(ws + 0);          // 16.78 MB, reused as zb after QKV GEMM
  u16*   zb    = xb;
  u16*   wt    = (u16*)(ws + 16777216);   // 6.29 MB
  u16*   wot   = (u16*)(ws + 23068672);   // 2.10 MB
  float* biasN = (float*)(ws + 25165824); // 12 KB
  float* mb    = (float*)(ws + 25178112); // 32 KB
  u16*   qb    = (u16*)(ws + 25210880);   // 16.78 MB
  u16*   kb    = (u16*)(ws + 41988096);   // 16.78 MB
  u16*   vtb   = (u16*)(ws + 58765312);   // 16.78 MB
  float* out   = (float*)d_out;

  k_prep<<<dim3(9248), dim3(256), 0, stream>>>(x, mask, Wq, Wk, Wv, bq, bk, bv, Wo,
                                               xb, wt, wot, biasN, mb);
  k_gemm_qkv<<<dim3(64, 24), dim3(256), 0, stream>>>(xb, wt, biasN, qb, kb, vtb);
  k_attn<<<dim3(512), dim3(256), 0, stream>>>(qb, kb, vtb, mb, zb);
  k_gemm_out<<<dim3(64, 8), dim3(256), 0, stream>>>(zb, wot, bo, out);
}